// Round 1
// baseline (2803.454 us; speedup 1.0000x reference)
//
#include <hip/hip_runtime.h>
#include <float.h>
#include <math.h>

#define BB 4
#define TT 2048
#define CC 1024
#define HH 16
#define HD 64
#define C3 3072

// ---------------------------------------------------------------- rope table
__global__ __launch_bounds__(256) void rope_table_k(float* __restrict__ tab) {
    int idx = blockIdx.x * 256 + threadIdx.x;
    if (idx >= TT * 32) return;
    int t = idx >> 5;
    int j = idx & 31;
    float freq = powf(10000.0f, -((float)(2 * j)) / 64.0f);
    float ang = (float)t * freq;
    tab[idx] = cosf(ang);
    tab[TT * 32 + idx] = sinf(ang);
}

// ---------------------------------------------------------------- fp32 GEMM
// C[M,N] = A[M,K] @ B[K,N], all row-major. 64x64 tile, 256 thr, 4x4/thread.
__global__ __launch_bounds__(256) void sgemm64(const float* __restrict__ A,
                                               const float* __restrict__ Bm,
                                               float* __restrict__ Cm,
                                               int M, int N, int K) {
    __shared__ float As[64][17];
    __shared__ float Bs[16][65];
    const int tid = threadIdx.x;
    const int tx = tid & 15, ty = tid >> 4;
    const int n0 = blockIdx.x * 64;
    const int m0 = blockIdx.y * 64;
    float acc[4][4] = {};
    for (int k0 = 0; k0 < K; k0 += 16) {
        {
            int r = tid >> 2, f = (tid & 3) * 4;
            float4 av = *(const float4*)(A + (size_t)(m0 + r) * K + k0 + f);
            As[r][f + 0] = av.x; As[r][f + 1] = av.y;
            As[r][f + 2] = av.z; As[r][f + 3] = av.w;
        }
        {
            int kr = tid >> 4, f = (tid & 15) * 4;
            float4 bv = *(const float4*)(Bm + (size_t)(k0 + kr) * N + n0 + f);
            Bs[kr][f + 0] = bv.x; Bs[kr][f + 1] = bv.y;
            Bs[kr][f + 2] = bv.z; Bs[kr][f + 3] = bv.w;
        }
        __syncthreads();
        #pragma unroll
        for (int kk = 0; kk < 16; ++kk) {
            float a0 = As[ty * 4 + 0][kk], a1 = As[ty * 4 + 1][kk];
            float a2 = As[ty * 4 + 2][kk], a3 = As[ty * 4 + 3][kk];
            float b0 = Bs[kk][tx * 4 + 0], b1 = Bs[kk][tx * 4 + 1];
            float b2 = Bs[kk][tx * 4 + 2], b3 = Bs[kk][tx * 4 + 3];
            acc[0][0] += a0 * b0; acc[0][1] += a0 * b1; acc[0][2] += a0 * b2; acc[0][3] += a0 * b3;
            acc[1][0] += a1 * b0; acc[1][1] += a1 * b1; acc[1][2] += a1 * b2; acc[1][3] += a1 * b3;
            acc[2][0] += a2 * b0; acc[2][1] += a2 * b1; acc[2][2] += a2 * b2; acc[2][3] += a2 * b3;
            acc[3][0] += a3 * b0; acc[3][1] += a3 * b1; acc[3][2] += a3 * b2; acc[3][3] += a3 * b3;
        }
        __syncthreads();
    }
    #pragma unroll
    for (int i = 0; i < 4; ++i) {
        float4 ov = make_float4(acc[i][0], acc[i][1], acc[i][2], acc[i][3]);
        *(float4*)(Cm + (size_t)(m0 + ty * 4 + i) * N + n0 + tx * 4) = ov;
    }
}

// ------------------------------------------- in-place RoPE + RMSnorm + v+emb
// qkv layout: (B*T, 3C). One block per row; wave handles one head (64 lanes).
__global__ __launch_bounds__(256) void rope_rms_k(float* __restrict__ qkv,
                                                  const float* __restrict__ val_embed,
                                                  const float* __restrict__ tab) {
    const int row = blockIdx.x;            // b*TT + t
    const int t = row & (TT - 1);
    const int lane = threadIdx.x & 63;
    const int wave = threadIdx.x >> 6;     // 0..3
    const int j = lane & 31;
    const float cs = tab[t * 32 + j];
    const float sn = tab[TT * 32 + t * 32 + j];
    float* base = qkv + (size_t)row * C3;
    for (int h = wave; h < HH; h += 4) {
        float qv = base[h * HD + lane];
        float kv = base[CC + h * HD + lane];
        float vv = base[2 * CC + h * HD + lane];
        float qp = __shfl_xor(qv, 32, 64);
        float kp = __shfl_xor(kv, 32, 64);
        float rq = (lane < 32) ? qv * cs - qp * sn : qv * cs + qp * sn;
        float rk = (lane < 32) ? kv * cs - kp * sn : kv * cs + kp * sn;
        float sq = rq * rq, sk = rk * rk;
        #pragma unroll
        for (int off = 1; off < 64; off <<= 1) {
            sq += __shfl_xor(sq, off, 64);
            sk += __shfl_xor(sk, off, 64);
        }
        rq *= rsqrtf(sq * (1.0f / 64.0f) + 1.1920929e-07f);
        rk *= rsqrtf(sk * (1.0f / 64.0f) + 1.1920929e-07f);
        base[h * HD + lane] = rq;
        base[CC + h * HD + lane] = rk;
        base[2 * CC + h * HD + lane] = vv + val_embed[(size_t)t * CC + h * HD + lane];
    }
}

// ------------------------------------------------- flash attention (causal)
// One block per (q-tile 64, b*h). 256 thr, 4x4 scores/outputs per thread.
__global__ __launch_bounds__(256) void attn_k(const float* __restrict__ qkv,
                                              float* __restrict__ y) {
    const int qt = blockIdx.x;             // q tile index (0..31)
    const int bh = blockIdx.y;             // b*HH + h
    const int b = bh >> 4, h = bh & 15;
    const int tid = threadIdx.x;
    const int tx = tid & 15, ty = tid >> 4;
    const float* qb = qkv + (size_t)b * TT * C3 + h * HD;
    const float* kb = qb + CC;
    const float* vb = qb + 2 * CC;
    __shared__ float Qs[64][65];
    __shared__ float KVs[64][65];
    __shared__ float Ps[64][65];
    // load Q tile (rows qt*64.., cols h*64.. of q section)
    for (int e = tid; e < 64 * 16; e += 256) {
        int r = e >> 4, c = (e & 15) * 4;
        float4 v4 = *(const float4*)(qb + (size_t)(qt * 64 + r) * C3 + c);
        Qs[r][c + 0] = v4.x; Qs[r][c + 1] = v4.y;
        Qs[r][c + 2] = v4.z; Qs[r][c + 3] = v4.w;
    }
    float m_r[4], l_r[4], yacc[4][4];
    #pragma unroll
    for (int i = 0; i < 4; ++i) {
        m_r[i] = -FLT_MAX; l_r[i] = 0.f;
        #pragma unroll
        for (int jj = 0; jj < 4; ++jj) yacc[i][jj] = 0.f;
    }
    for (int kt = 0; kt <= qt; ++kt) {
        __syncthreads();   // previous PV reads of KVs/Ps complete
        // load K tile
        for (int e = tid; e < 64 * 16; e += 256) {
            int r = e >> 4, c = (e & 15) * 4;
            float4 v4 = *(const float4*)(kb + (size_t)(kt * 64 + r) * C3 + c);
            KVs[r][c + 0] = v4.x; KVs[r][c + 1] = v4.y;
            KVs[r][c + 2] = v4.z; KVs[r][c + 3] = v4.w;
        }
        __syncthreads();
        // S = Q @ K^T  (4x4 per thread)
        float s[4][4] = {};
        for (int d = 0; d < 64; ++d) {
            float a0 = Qs[ty * 4 + 0][d], a1 = Qs[ty * 4 + 1][d];
            float a2 = Qs[ty * 4 + 2][d], a3 = Qs[ty * 4 + 3][d];
            float b0 = KVs[tx * 4 + 0][d], b1 = KVs[tx * 4 + 1][d];
            float b2 = KVs[tx * 4 + 2][d], b3 = KVs[tx * 4 + 3][d];
            s[0][0] += a0 * b0; s[0][1] += a0 * b1; s[0][2] += a0 * b2; s[0][3] += a0 * b3;
            s[1][0] += a1 * b0; s[1][1] += a1 * b1; s[1][2] += a1 * b2; s[1][3] += a1 * b3;
            s[2][0] += a2 * b0; s[2][1] += a2 * b1; s[2][2] += a2 * b2; s[2][3] += a2 * b3;
            s[3][0] += a3 * b0; s[3][1] += a3 * b1; s[3][2] += a3 * b2; s[3][3] += a3 * b3;
        }
        const bool diag = (kt == qt);
        #pragma unroll
        for (int i = 0; i < 4; ++i) {
            #pragma unroll
            for (int jj = 0; jj < 4; ++jj) {
                s[i][jj] *= 0.125f;
                if (diag && (tx * 4 + jj > ty * 4 + i)) s[i][jj] = -1e30f;
            }
        }
        // online softmax per row (rows live on 16 contiguous lanes: shfl over tx)
        #pragma unroll
        for (int i = 0; i < 4; ++i) {
            float rm = fmaxf(fmaxf(s[i][0], s[i][1]), fmaxf(s[i][2], s[i][3]));
            #pragma unroll
            for (int off = 1; off < 16; off <<= 1) rm = fmaxf(rm, __shfl_xor(rm, off, 64));
            float mnew = fmaxf(m_r[i], rm);
            float alpha = __expf(m_r[i] - mnew);
            m_r[i] = mnew;
            float rs = 0.f;
            #pragma unroll
            for (int jj = 0; jj < 4; ++jj) {
                float p = __expf(s[i][jj] - mnew);
                s[i][jj] = p;
                rs += p;
            }
            #pragma unroll
            for (int off = 1; off < 16; off <<= 1) rs += __shfl_xor(rs, off, 64);
            l_r[i] = l_r[i] * alpha + rs;
            #pragma unroll
            for (int jj = 0; jj < 4; ++jj) yacc[i][jj] *= alpha;
        }
        __syncthreads();   // S-phase reads of KVs complete
        // stash P, load V tile over K tile
        #pragma unroll
        for (int i = 0; i < 4; ++i)
            #pragma unroll
            for (int jj = 0; jj < 4; ++jj)
                Ps[ty * 4 + i][tx * 4 + jj] = s[i][jj];
        for (int e = tid; e < 64 * 16; e += 256) {
            int r = e >> 4, c = (e & 15) * 4;
            float4 v4 = *(const float4*)(vb + (size_t)(kt * 64 + r) * C3 + c);
            KVs[r][c + 0] = v4.x; KVs[r][c + 1] = v4.y;
            KVs[r][c + 2] = v4.z; KVs[r][c + 3] = v4.w;
        }
        __syncthreads();
        // yacc += P @ V
        for (int d = 0; d < 64; ++d) {
            float p0 = Ps[ty * 4 + 0][d], p1 = Ps[ty * 4 + 1][d];
            float p2 = Ps[ty * 4 + 2][d], p3 = Ps[ty * 4 + 3][d];
            float v0 = KVs[d][tx * 4 + 0], v1 = KVs[d][tx * 4 + 1];
            float v2 = KVs[d][tx * 4 + 2], v3 = KVs[d][tx * 4 + 3];
            yacc[0][0] += p0 * v0; yacc[0][1] += p0 * v1; yacc[0][2] += p0 * v2; yacc[0][3] += p0 * v3;
            yacc[1][0] += p1 * v0; yacc[1][1] += p1 * v1; yacc[1][2] += p1 * v2; yacc[1][3] += p1 * v3;
            yacc[2][0] += p2 * v0; yacc[2][1] += p2 * v1; yacc[2][2] += p2 * v2; yacc[2][3] += p2 * v3;
            yacc[3][0] += p3 * v0; yacc[3][1] += p3 * v1; yacc[3][2] += p3 * v2; yacc[3][3] += p3 * v3;
        }
    }
    // epilogue: divide by l, write y in (B,T,C) layout
    #pragma unroll
    for (int i = 0; i < 4; ++i) {
        float inv = 1.0f / l_r[i];
        int qrow = qt * 64 + ty * 4 + i;
        float4 ov = make_float4(yacc[i][0] * inv, yacc[i][1] * inv,
                                yacc[i][2] * inv, yacc[i][3] * inv);
        *(float4*)(y + ((size_t)(b * TT + qrow)) * CC + h * HD + tx * 4) = ov;
    }
}

extern "C" void kernel_launch(void* const* d_in, const int* in_sizes, int n_in,
                              void* d_out, int out_size, void* d_ws, size_t ws_size,
                              hipStream_t stream) {
    const float* x         = (const float*)d_in[0];
    const float* w_attn    = (const float*)d_in[1];
    const float* w_proj    = (const float*)d_in[2];
    const float* val_embed = (const float*)d_in[3];
    float* out = (float*)d_out;
    float* ws  = (float*)d_ws;

    float* qkv  = ws;                                   // B*T*3C   = 25165824 f
    float* ybuf = qkv + (size_t)BB * TT * C3;           // B*T*C    =  8388608 f
    float* tab  = ybuf + (size_t)BB * TT * CC;          // 2*T*32   =   131072 f

    rope_table_k<<<dim3((TT * 32 + 255) / 256), dim3(256), 0, stream>>>(tab);
    sgemm64<<<dim3(C3 / 64, BB * TT / 64), dim3(256), 0, stream>>>(
        x, w_attn, qkv, BB * TT, C3, CC);
    rope_rms_k<<<dim3(BB * TT), dim3(256), 0, stream>>>(qkv, val_embed, tab);
    attn_k<<<dim3(TT / 64, BB * HH), dim3(256), 0, stream>>>(qkv, ybuf);
    sgemm64<<<dim3(CC / 64, BB * TT / 64), dim3(256), 0, stream>>>(
        ybuf, w_proj, out, BB * TT, CC, CC);
}

// Round 2
// 363.596 us; speedup vs baseline: 7.7104x; 7.7104x over previous
//
#include <hip/hip_runtime.h>
#include <float.h>
#include <math.h>

#define BB 4
#define TT 2048
#define CC 1024
#define HH 16
#define HD 64
#define C3 3072
#define MTOT (BB*TT)

typedef __bf16 bf16;
typedef __bf16 bf16x8 __attribute__((ext_vector_type(8)));
typedef float f32x4 __attribute__((ext_vector_type(4)));

__device__ __forceinline__ void gload16(const void* g, void* l) {
    __builtin_amdgcn_global_load_lds(
        (const __attribute__((address_space(1))) void*)g,
        (__attribute__((address_space(3))) void*)l, 16, 0, 0);
}

// ---------------------------------------------------------------- rope table
__global__ __launch_bounds__(256) void rope_table_k(float* __restrict__ tab) {
    int idx = blockIdx.x * 256 + threadIdx.x;
    if (idx >= TT * 32) return;
    int t = idx >> 5;
    int j = idx & 31;
    float freq = powf(10000.0f, -((float)(2 * j)) / 64.0f);
    float ang = (float)t * freq;
    tab[idx] = cosf(ang);
    tab[TT * 32 + idx] = sinf(ang);
}

// ------------------------------------------------------------- x fp32->bf16
__global__ __launch_bounds__(256) void cvt_f2b_k(const float* __restrict__ in,
                                                 bf16* __restrict__ out, int n8) {
    int i = blockIdx.x * 256 + threadIdx.x;
    if (i >= n8) return;
    const float4* p = (const float4*)(in + (size_t)i * 8);
    float4 a = p[0], b = p[1];
    bf16x8 o;
    o[0] = (bf16)a.x; o[1] = (bf16)a.y; o[2] = (bf16)a.z; o[3] = (bf16)a.w;
    o[4] = (bf16)b.x; o[5] = (bf16)b.y; o[6] = (bf16)b.z; o[7] = (bf16)b.w;
    *(bf16x8*)(out + (size_t)i * 8) = o;
}

// -------------------------------------- W [K][N] fp32 -> WT [N][K] bf16
__global__ __launch_bounds__(256) void transW_k(const float* __restrict__ in,
                                                bf16* __restrict__ out, int K, int N) {
    __shared__ bf16 tile[64][72];
    int n0 = blockIdx.x * 64, k0 = blockIdx.y * 64;
    int t = threadIdx.x;
    int r = t >> 2, c4 = (t & 3) * 16;
    const float4* src = (const float4*)(in + (size_t)(k0 + r) * N + n0 + c4);
    #pragma unroll
    for (int j = 0; j < 4; ++j) {
        float4 v = src[j];
        tile[r][c4 + 4 * j + 0] = (bf16)v.x; tile[r][c4 + 4 * j + 1] = (bf16)v.y;
        tile[r][c4 + 4 * j + 2] = (bf16)v.z; tile[r][c4 + 4 * j + 3] = (bf16)v.w;
    }
    __syncthreads();
    bf16x8 o0, o1;
    #pragma unroll
    for (int j = 0; j < 8; ++j) o0[j] = tile[c4 + j][r];
    #pragma unroll
    for (int j = 0; j < 8; ++j) o1[j] = tile[c4 + 8 + j][r];
    *(bf16x8*)(out + (size_t)(n0 + r) * K + k0 + c4) = o0;
    *(bf16x8*)(out + (size_t)(n0 + r) * K + k0 + c4 + 8) = o1;
}

// -------------------------------------- Vh [bh][T][64] -> Vt [bh][64][T] bf16
__global__ __launch_bounds__(256) void transV_k(const bf16* __restrict__ Vh,
                                                bf16* __restrict__ Vt) {
    __shared__ bf16 tile[64][72];
    int t0 = blockIdx.x * 64, bh = blockIdx.y;
    const bf16* in = Vh + (size_t)bh * TT * HD;
    bf16* out = Vt + (size_t)bh * HD * TT;
    int t = threadIdx.x;
    int r = t >> 2, c4 = (t & 3) * 16;
    bf16x8 a = *(const bf16x8*)(in + (size_t)(t0 + r) * HD + c4);
    bf16x8 b = *(const bf16x8*)(in + (size_t)(t0 + r) * HD + c4 + 8);
    #pragma unroll
    for (int j = 0; j < 8; ++j) tile[r][c4 + j] = a[j];
    #pragma unroll
    for (int j = 0; j < 8; ++j) tile[r][c4 + 8 + j] = b[j];
    __syncthreads();
    bf16x8 o0, o1;
    #pragma unroll
    for (int j = 0; j < 8; ++j) o0[j] = tile[c4 + j][r];
    #pragma unroll
    for (int j = 0; j < 8; ++j) o1[j] = tile[c4 + 8 + j][r];
    *(bf16x8*)(out + (size_t)r * TT + t0 + c4) = o0;
    *(bf16x8*)(out + (size_t)r * TT + t0 + c4 + 8) = o1;
}

// ------------------------------------------------------- bf16 MFMA GEMM (BT)
// C = A[M,K] @ BT[N,K]^T. 128x128 tile, BK=64, 4 waves, 64x64/wave.
// epi==0: C fp32 [M][N].  epi==1: scatter to Qh/Kh/Vh [bh][T][64] bf16.
__global__ __launch_bounds__(256) void gemm_bt_k(const bf16* __restrict__ A,
                                                 const bf16* __restrict__ BT,
                                                 float* __restrict__ C,
                                                 bf16* __restrict__ Qh,
                                                 bf16* __restrict__ Kh,
                                                 bf16* __restrict__ Vh,
                                                 int M, int N, int K, int epi) {
    __shared__ bf16 Al[128 * 64];
    __shared__ bf16 Bl[128 * 64];
    const int tid = threadIdx.x;
    const int w = tid >> 6, lane = tid & 63;
    const int m0 = blockIdx.y * 128, n0 = blockIdx.x * 128;
    const int wrow = (w >> 1) * 64, wcol = (w & 1) * 64;
    const int srow = lane >> 3;
    const int selem = (((lane & 7) ^ srow) << 3);
    const int xorL = (lane & 7) << 3;

    const f32x4 fz = {0.f, 0.f, 0.f, 0.f};
    f32x4 acc[4][4];
    #pragma unroll
    for (int i = 0; i < 4; ++i)
        #pragma unroll
        for (int j = 0; j < 4; ++j) acc[i][j] = fz;

    for (int k0 = 0; k0 < K; k0 += 64) {
        __syncthreads();
        #pragma unroll
        for (int jj = 0; jj < 4; ++jj) {
            int c = w * 4 + jj;
            int row = c * 8 + srow;
            gload16(A + (size_t)(m0 + row) * K + k0 + selem, &Al[c * 512]);
            gload16(BT + (size_t)(n0 + row) * K + k0 + selem, &Bl[c * 512]);
        }
        __syncthreads();
        #pragma unroll
        for (int kh = 0; kh < 2; ++kh) {
            const int off = (kh * 32 + (lane >> 4) * 8) ^ xorL;
            bf16x8 aF[4], bF[4];
            #pragma unroll
            for (int i = 0; i < 4; ++i) {
                aF[i] = *(const bf16x8*)&Al[(wrow + i * 16 + (lane & 15)) * 64 + off];
                bF[i] = *(const bf16x8*)&Bl[(wcol + i * 16 + (lane & 15)) * 64 + off];
            }
            #pragma unroll
            for (int i = 0; i < 4; ++i)
                #pragma unroll
                for (int j = 0; j < 4; ++j)
                    acc[i][j] = __builtin_amdgcn_mfma_f32_16x16x32_bf16(
                        aF[i], bF[j], acc[i][j], 0, 0, 0);
        }
    }

    if (epi == 0) {
        #pragma unroll
        for (int i = 0; i < 4; ++i)
            #pragma unroll
            for (int r = 0; r < 4; ++r) {
                size_t rowm = (size_t)(m0 + wrow + i * 16 + 4 * (lane >> 4) + r);
                #pragma unroll
                for (int j = 0; j < 4; ++j)
                    C[rowm * N + n0 + wcol + j * 16 + (lane & 15)] = acc[i][j][r];
            }
    } else {
        int ncb = n0 + wcol;
        int region = ncb >> 10;
        int h = (ncb & 1023) >> 6;
        bf16* dst = (region == 0) ? Qh : ((region == 1) ? Kh : Vh);
        #pragma unroll
        for (int i = 0; i < 4; ++i)
            #pragma unroll
            for (int r = 0; r < 4; ++r) {
                int m = m0 + wrow + i * 16 + 4 * (lane >> 4) + r;
                int b = m >> 11, t = m & (TT - 1);
                size_t rb = ((size_t)(b * HH + h) * TT + t) * HD;
                #pragma unroll
                for (int j = 0; j < 4; ++j)
                    dst[rb + j * 16 + (lane & 15)] = (bf16)acc[i][j][r];
            }
    }
}

// ----------------------------------- in-place RoPE + RMS on Qh/Kh, emb on Vh
__global__ __launch_bounds__(256) void rope_rms_k(bf16* __restrict__ Qh,
                                                  bf16* __restrict__ Kh,
                                                  bf16* __restrict__ Vh,
                                                  const float* __restrict__ emb,
                                                  const float* __restrict__ tab) {
    const int wave = threadIdx.x >> 6, lane = threadIdx.x & 63;
    const int row = blockIdx.x * 4 + wave;      // 0 .. B*H*T-1
    const int t = row & (TT - 1);
    const int h = (row >> 11) & (HH - 1);
    const size_t base = (size_t)row * HD + lane;
    const int j = lane & 31;
    const float cs = tab[t * 32 + j];
    const float sn = tab[TT * 32 + t * 32 + j];
    float q = (float)Qh[base], k = (float)Kh[base], v = (float)Vh[base];
    float qp = __shfl_xor(q, 32, 64), kp = __shfl_xor(k, 32, 64);
    float rq = (lane < 32) ? q * cs - qp * sn : q * cs + qp * sn;
    float rk = (lane < 32) ? k * cs - kp * sn : k * cs + kp * sn;
    float sq = rq * rq, sk = rk * rk;
    #pragma unroll
    for (int off = 1; off < 64; off <<= 1) {
        sq += __shfl_xor(sq, off, 64);
        sk += __shfl_xor(sk, off, 64);
    }
    rq *= rsqrtf(sq * (1.0f / 64.0f) + 1.1920929e-07f);
    rk *= rsqrtf(sk * (1.0f / 64.0f) + 1.1920929e-07f);
    Qh[base] = (bf16)rq;
    Kh[base] = (bf16)rk;
    Vh[base] = (bf16)(v + emb[(size_t)t * CC + h * HD + lane]);
}

// ------------------------------------------------ MFMA flash attn (causal)
// grid (T/64, B*H), 4 waves; wave w owns 16 q rows. KV tile = 64.
__global__ __launch_bounds__(256) void attn_k(const bf16* __restrict__ Qh,
                                              const bf16* __restrict__ Kh,
                                              const bf16* __restrict__ Vt,
                                              bf16* __restrict__ Y) {
    const int qt = blockIdx.x, bh = blockIdx.y;
    const int b = bh >> 4, h = bh & 15;
    const int tid = threadIdx.x, w = tid >> 6, lane = tid & 63;
    __shared__ bf16 Kl[64 * 64];
    __shared__ bf16 Vl[64 * 64];
    __shared__ bf16 Pl[4][16 * 64];
    const bf16* Kbase = Kh + (size_t)bh * TT * HD;
    const bf16* Vbase = Vt + (size_t)bh * HD * TT;
    const int srow = lane >> 3;
    const int selem = (((lane & 7) ^ srow) << 3);
    const int xorL = (lane & 7) << 3;

    bf16x8 qF[2];
    {
        int qrow = qt * 64 + w * 16 + (lane & 15);
        const bf16* qp = Qh + (size_t)bh * TT * HD + (size_t)qrow * HD + (lane >> 4) * 8;
        qF[0] = *(const bf16x8*)qp;
        qF[1] = *(const bf16x8*)(qp + 32);
    }
    const f32x4 fz = {0.f, 0.f, 0.f, 0.f};
    f32x4 accY[4];
    float mR[4], lR[4];
    #pragma unroll
    for (int r = 0; r < 4; ++r) { accY[r] = fz; mR[r] = -1e30f; lR[r] = 0.f; }

    for (int kt = 0; kt <= qt; ++kt) {
        __syncthreads();
        #pragma unroll
        for (int jj = 0; jj < 2; ++jj) {
            int c = w * 2 + jj;
            int row = c * 8 + srow;
            gload16(Kbase + (size_t)(kt * 64 + row) * HD + selem, &Kl[c * 512]);
            gload16(Vbase + (size_t)row * TT + kt * 64 + selem, &Vl[c * 512]);
        }
        __syncthreads();
        // S = Q @ K^T
        f32x4 s[4];
        #pragma unroll
        for (int ct = 0; ct < 4; ++ct) {
            s[ct] = fz;
            #pragma unroll
            for (int kh = 0; kh < 2; ++kh) {
                bf16x8 kF = *(const bf16x8*)
                    &Kl[(ct * 16 + (lane & 15)) * 64 + ((kh * 32 + (lane >> 4) * 8) ^ xorL)];
                s[ct] = __builtin_amdgcn_mfma_f32_16x16x32_bf16(qF[kh], kF, s[ct], 0, 0, 0);
            }
        }
        const bool diag = (kt == qt);
        #pragma unroll
        for (int ct = 0; ct < 4; ++ct)
            #pragma unroll
            for (int r = 0; r < 4; ++r) {
                float v = s[ct][r] * 0.125f;
                if (diag) {
                    int qg = w * 16 + 4 * (lane >> 4) + r;
                    int kg = ct * 16 + (lane & 15);
                    if (kg > qg) v = -1e30f;
                }
                s[ct][r] = v;
            }
        // online softmax per q-row
        float al[4];
        #pragma unroll
        for (int r = 0; r < 4; ++r) {
            float rm = fmaxf(fmaxf(s[0][r], s[1][r]), fmaxf(s[2][r], s[3][r]));
            rm = fmaxf(rm, __shfl_xor(rm, 1, 64));
            rm = fmaxf(rm, __shfl_xor(rm, 2, 64));
            rm = fmaxf(rm, __shfl_xor(rm, 4, 64));
            rm = fmaxf(rm, __shfl_xor(rm, 8, 64));
            float mn = fmaxf(mR[r], rm);
            float a = __expf(mR[r] - mn);
            mR[r] = mn;
            float rs = 0.f;
            #pragma unroll
            for (int ct = 0; ct < 4; ++ct) {
                float p = __expf(s[ct][r] - mn);
                s[ct][r] = p;
                rs += p;
            }
            rs += __shfl_xor(rs, 1, 64);
            rs += __shfl_xor(rs, 2, 64);
            rs += __shfl_xor(rs, 4, 64);
            rs += __shfl_xor(rs, 8, 64);
            lR[r] = lR[r] * a + rs;
            al[r] = a;
        }
        #pragma unroll
        for (int cd = 0; cd < 4; ++cd)
            #pragma unroll
            for (int r = 0; r < 4; ++r) accY[cd][r] *= al[r];
        // P -> LDS (bf16, swizzled)
        #pragma unroll
        for (int ct = 0; ct < 4; ++ct)
            #pragma unroll
            for (int r = 0; r < 4; ++r) {
                int prow = 4 * (lane >> 4) + r;
                Pl[w][prow * 64 + ((ct * 16 + (lane & 15)) ^ ((prow & 7) << 3))] =
                    (bf16)s[ct][r];
            }
        // PV
        bf16x8 pF[2];
        pF[0] = *(const bf16x8*)&Pl[w][(lane & 15) * 64 + (((lane >> 4) * 8) ^ xorL)];
        pF[1] = *(const bf16x8*)&Pl[w][(lane & 15) * 64 + ((32 + (lane >> 4) * 8) ^ xorL)];
        #pragma unroll
        for (int cd = 0; cd < 4; ++cd) {
            #pragma unroll
            for (int kvh = 0; kvh < 2; ++kvh) {
                bf16x8 vF = *(const bf16x8*)
                    &Vl[(cd * 16 + (lane & 15)) * 64 + ((kvh * 32 + (lane >> 4) * 8) ^ xorL)];
                accY[cd] = __builtin_amdgcn_mfma_f32_16x16x32_bf16(pF[kvh], vF, accY[cd], 0, 0, 0);
            }
        }
    }
    #pragma unroll
    for (int cd = 0; cd < 4; ++cd)
        #pragma unroll
        for (int r = 0; r < 4; ++r) {
            int qg = qt * 64 + w * 16 + 4 * (lane >> 4) + r;
            Y[((size_t)(b * TT + qg)) * CC + h * HD + cd * 16 + (lane & 15)] =
                (bf16)(accY[cd][r] / lR[r]);
        }
}

extern "C" void kernel_launch(void* const* d_in, const int* in_sizes, int n_in,
                              void* d_out, int out_size, void* d_ws, size_t ws_size,
                              hipStream_t stream) {
    const float* x         = (const float*)d_in[0];
    const float* w_attn    = (const float*)d_in[1];
    const float* w_proj    = (const float*)d_in[2];
    const float* val_embed = (const float*)d_in[3];
    float* out = (float*)d_out;

    bf16* xb  = (bf16*)d_ws;                        // 8192*1024
    bf16* waT = xb + (size_t)8192 * 1024;           // 3072*1024
    bf16* wpT = waT + (size_t)3072 * 1024;          // 1024*1024
    bf16* Qh  = wpT + (size_t)1024 * 1024;          // 64*2048*64
    bf16* Kh  = Qh + (size_t)64 * 2048 * 64;
    bf16* Vh  = Kh + (size_t)64 * 2048 * 64;
    bf16* Vt  = Vh + (size_t)64 * 2048 * 64;
    bf16* Yb  = Vt + (size_t)64 * 2048 * 64;
    float* tab = (float*)(Yb + (size_t)64 * 2048 * 64);  // 2*2048*32 f32

    rope_table_k<<<dim3((TT * 32 + 255) / 256), dim3(256), 0, stream>>>(tab);
    cvt_f2b_k<<<dim3(8192 * 1024 / 8 / 256), dim3(256), 0, stream>>>(x, xb, 8192 * 1024 / 8);
    transW_k<<<dim3(3072 / 64, 1024 / 64), dim3(256), 0, stream>>>(w_attn, waT, 1024, 3072);
    transW_k<<<dim3(1024 / 64, 1024 / 64), dim3(256), 0, stream>>>(w_proj, wpT, 1024, 1024);
    gemm_bt_k<<<dim3(3072 / 128, 8192 / 128), dim3(256), 0, stream>>>(
        xb, waT, nullptr, Qh, Kh, Vh, 8192, 3072, 1024, 1);
    rope_rms_k<<<dim3(BB * HH * TT / 4), dim3(256), 0, stream>>>(Qh, Kh, Vh, val_embed, tab);
    transV_k<<<dim3(TT / 64, BB * HH), dim3(256), 0, stream>>>(Vh, Vt);
    attn_k<<<dim3(TT / 64, BB * HH), dim3(256), 0, stream>>>(Qh, Kh, Vt, Yb);
    gemm_bt_k<<<dim3(1024 / 128, 8192 / 128), dim3(256), 0, stream>>>(
        Yb, wpT, out, nullptr, nullptr, nullptr, 8192, 1024, 1024, 0);
}

// Round 3
// 243.652 us; speedup vs baseline: 11.5060x; 1.4923x over previous
//
#include <hip/hip_runtime.h>
#include <float.h>
#include <math.h>

#define BB 4
#define TT 2048
#define CC 1024
#define HH 16
#define HD 64
#define C3 3072

typedef __bf16 bf16;
typedef __bf16 bf16x8 __attribute__((ext_vector_type(8)));
typedef __bf16 bf16x4 __attribute__((ext_vector_type(4)));
typedef float f32x4 __attribute__((ext_vector_type(4)));
typedef float f32x16 __attribute__((ext_vector_type(16)));
typedef unsigned int uint32x4 __attribute__((ext_vector_type(4)));

__device__ __forceinline__ void gload16(const void* g, void* l) {
    __builtin_amdgcn_global_load_lds(
        (const __attribute__((address_space(1))) void*)g,
        (__attribute__((address_space(3))) void*)l, 16, 0, 0);
}

// ---------------------------------------------------------------- rope table
__global__ __launch_bounds__(256) void rope_table_k(float* __restrict__ tab) {
    int idx = blockIdx.x * 256 + threadIdx.x;
    if (idx >= TT * 32) return;
    int t = idx >> 5;
    int j = idx & 31;
    float freq = powf(10000.0f, -((float)(2 * j)) / 64.0f);
    float ang = (float)t * freq;
    tab[idx] = cosf(ang);
    tab[TT * 32 + idx] = sinf(ang);
}

// ------------------------------------------------------------- x fp32->bf16
__global__ __launch_bounds__(256) void cvt_f2b_k(const float* __restrict__ in,
                                                 bf16* __restrict__ out, int n8) {
    int i = blockIdx.x * 256 + threadIdx.x;
    if (i >= n8) return;
    const float4* p = (const float4*)(in + (size_t)i * 8);
    float4 a = p[0], b = p[1];
    bf16x8 o;
    o[0] = (bf16)a.x; o[1] = (bf16)a.y; o[2] = (bf16)a.z; o[3] = (bf16)a.w;
    o[4] = (bf16)b.x; o[5] = (bf16)b.y; o[6] = (bf16)b.z; o[7] = (bf16)b.w;
    *(bf16x8*)(out + (size_t)i * 8) = o;
}

// -------------------------------------- W [K][N] fp32 -> WT [N][K] bf16
__global__ __launch_bounds__(256) void transW_k(const float* __restrict__ in,
                                                bf16* __restrict__ out, int K, int N) {
    __shared__ bf16 tile[64][72];
    int n0 = blockIdx.x * 64, k0 = blockIdx.y * 64;
    int t = threadIdx.x;
    int r = t >> 2, c4 = (t & 3) * 16;
    const float4* src = (const float4*)(in + (size_t)(k0 + r) * N + n0 + c4);
    #pragma unroll
    for (int j = 0; j < 4; ++j) {
        float4 v = src[j];
        tile[r][c4 + 4 * j + 0] = (bf16)v.x; tile[r][c4 + 4 * j + 1] = (bf16)v.y;
        tile[r][c4 + 4 * j + 2] = (bf16)v.z; tile[r][c4 + 4 * j + 3] = (bf16)v.w;
    }
    __syncthreads();
    bf16x8 o0, o1;
    #pragma unroll
    for (int j = 0; j < 8; ++j) o0[j] = tile[c4 + j][r];
    #pragma unroll
    for (int j = 0; j < 8; ++j) o1[j] = tile[c4 + 8 + j][r];
    *(bf16x8*)(out + (size_t)(n0 + r) * K + k0 + c4) = o0;
    *(bf16x8*)(out + (size_t)(n0 + r) * K + k0 + c4 + 8) = o1;
}

// -------------------------------------- Vh [bh][T][64] -> Vt [bh][64][T] bf16
__global__ __launch_bounds__(256) void transV_k(const bf16* __restrict__ Vh,
                                                bf16* __restrict__ Vt) {
    __shared__ bf16 tile[64][72];
    int t0 = blockIdx.x * 64, bh = blockIdx.y;
    const bf16* in = Vh + (size_t)bh * TT * HD;
    bf16* out = Vt + (size_t)bh * HD * TT;
    int t = threadIdx.x;
    int r = t >> 2, c4 = (t & 3) * 16;
    bf16x8 a = *(const bf16x8*)(in + (size_t)(t0 + r) * HD + c4);
    bf16x8 b = *(const bf16x8*)(in + (size_t)(t0 + r) * HD + c4 + 8);
    #pragma unroll
    for (int j = 0; j < 8; ++j) tile[r][c4 + j] = a[j];
    #pragma unroll
    for (int j = 0; j < 8; ++j) tile[r][c4 + 8 + j] = b[j];
    __syncthreads();
    bf16x8 o0, o1;
    #pragma unroll
    for (int j = 0; j < 8; ++j) o0[j] = tile[c4 + j][r];
    #pragma unroll
    for (int j = 0; j < 8; ++j) o1[j] = tile[c4 + 8 + j][r];
    *(bf16x8*)(out + (size_t)r * TT + t0 + c4) = o0;
    *(bf16x8*)(out + (size_t)r * TT + t0 + c4 + 8) = o1;
}

// ------------------------------------------------------- bf16 MFMA GEMM (BT)
__global__ __launch_bounds__(256) void gemm_bt_k(const bf16* __restrict__ A,
                                                 const bf16* __restrict__ BT,
                                                 float* __restrict__ C,
                                                 bf16* __restrict__ Qh,
                                                 bf16* __restrict__ Kh,
                                                 bf16* __restrict__ Vh,
                                                 int M, int N, int K, int epi) {
    __shared__ bf16 Al[128 * 64];
    __shared__ bf16 Bl[128 * 64];
    const int tid = threadIdx.x;
    const int w = tid >> 6, lane = tid & 63;
    const int m0 = blockIdx.y * 128, n0 = blockIdx.x * 128;
    const int wrow = (w >> 1) * 64, wcol = (w & 1) * 64;
    const int srow = lane >> 3;
    const int selem = (((lane & 7) ^ srow) << 3);
    const int xorL = (lane & 7) << 3;

    const f32x4 fz = {0.f, 0.f, 0.f, 0.f};
    f32x4 acc[4][4];
    #pragma unroll
    for (int i = 0; i < 4; ++i)
        #pragma unroll
        for (int j = 0; j < 4; ++j) acc[i][j] = fz;

    for (int k0 = 0; k0 < K; k0 += 64) {
        __syncthreads();
        #pragma unroll
        for (int jj = 0; jj < 4; ++jj) {
            int c = w * 4 + jj;
            int row = c * 8 + srow;
            gload16(A + (size_t)(m0 + row) * K + k0 + selem, &Al[c * 512]);
            gload16(BT + (size_t)(n0 + row) * K + k0 + selem, &Bl[c * 512]);
        }
        __syncthreads();
        #pragma unroll
        for (int kh = 0; kh < 2; ++kh) {
            const int off = (kh * 32 + (lane >> 4) * 8) ^ xorL;
            bf16x8 aF[4], bF[4];
            #pragma unroll
            for (int i = 0; i < 4; ++i) {
                aF[i] = *(const bf16x8*)&Al[(wrow + i * 16 + (lane & 15)) * 64 + off];
                bF[i] = *(const bf16x8*)&Bl[(wcol + i * 16 + (lane & 15)) * 64 + off];
            }
            #pragma unroll
            for (int i = 0; i < 4; ++i)
                #pragma unroll
                for (int j = 0; j < 4; ++j)
                    acc[i][j] = __builtin_amdgcn_mfma_f32_16x16x32_bf16(
                        aF[i], bF[j], acc[i][j], 0, 0, 0);
        }
    }

    if (epi == 0) {
        #pragma unroll
        for (int i = 0; i < 4; ++i)
            #pragma unroll
            for (int r = 0; r < 4; ++r) {
                size_t rowm = (size_t)(m0 + wrow + i * 16 + 4 * (lane >> 4) + r);
                #pragma unroll
                for (int j = 0; j < 4; ++j)
                    C[rowm * N + n0 + wcol + j * 16 + (lane & 15)] = acc[i][j][r];
            }
    } else {
        int ncb = n0 + wcol;
        int region = ncb >> 10;
        int h = (ncb & 1023) >> 6;
        bf16* dst = (region == 0) ? Qh : ((region == 1) ? Kh : Vh);
        #pragma unroll
        for (int i = 0; i < 4; ++i)
            #pragma unroll
            for (int r = 0; r < 4; ++r) {
                int m = m0 + wrow + i * 16 + 4 * (lane >> 4) + r;
                int b = m >> 11, t = m & (TT - 1);
                size_t rb = ((size_t)(b * HH + h) * TT + t) * HD;
                #pragma unroll
                for (int j = 0; j < 4; ++j)
                    dst[rb + j * 16 + (lane & 15)] = (bf16)acc[i][j][r];
            }
    }
}

// ----------------------------------- in-place RoPE + RMS on Qh/Kh, emb on Vh
// Q is additionally scaled by 0.125 (1/sqrt(64)) — exact in bf16.
__global__ __launch_bounds__(256) void rope_rms_k(bf16* __restrict__ Qh,
                                                  bf16* __restrict__ Kh,
                                                  bf16* __restrict__ Vh,
                                                  const float* __restrict__ emb,
                                                  const float* __restrict__ tab) {
    const int wave = threadIdx.x >> 6, lane = threadIdx.x & 63;
    const int row = blockIdx.x * 4 + wave;      // 0 .. B*H*T-1
    const int t = row & (TT - 1);
    const int h = (row >> 11) & (HH - 1);
    const size_t base = (size_t)row * HD + lane;
    const int j = lane & 31;
    const float cs = tab[t * 32 + j];
    const float sn = tab[TT * 32 + t * 32 + j];
    float q = (float)Qh[base], k = (float)Kh[base], v = (float)Vh[base];
    float qp = __shfl_xor(q, 32, 64), kp = __shfl_xor(k, 32, 64);
    float rq = (lane < 32) ? q * cs - qp * sn : q * cs + qp * sn;
    float rk = (lane < 32) ? k * cs - kp * sn : k * cs + kp * sn;
    float sq = rq * rq, sk = rk * rk;
    #pragma unroll
    for (int off = 1; off < 64; off <<= 1) {
        sq += __shfl_xor(sq, off, 64);
        sk += __shfl_xor(sk, off, 64);
    }
    rq *= rsqrtf(sq * (1.0f / 64.0f) + 1.1920929e-07f);
    rk *= rsqrtf(sk * (1.0f / 64.0f) + 1.1920929e-07f);
    Qh[base] = (bf16)(rq * 0.125f);
    Kh[base] = (bf16)rk;
    Vh[base] = (bf16)(v + emb[(size_t)t * CC + h * HD + lane]);
}

// ------------------------------------------------ MFMA flash attn (causal)
// 8 waves x 32 q-rows = 256 q rows/block. Swapped QK^T (S^T = K*Q^T) via
// 32x32x16 MFMA -> in-register softmax. PV swapped (Y^T = V^T * P^T).
__global__ __launch_bounds__(512) void attn_k(const bf16* __restrict__ Qh,
                                              const bf16* __restrict__ Kh,
                                              const bf16* __restrict__ Vt,
                                              bf16* __restrict__ Y) {
    const int qb = (int)(gridDim.x - 1) - (int)blockIdx.x;   // LPT: heavy first
    const int bh = blockIdx.y;
    const int b = bh >> 4, h = bh & 15;
    const int tid = threadIdx.x, w = tid >> 6, lane = tid & 63;
    const int hi = lane >> 5, q31 = lane & 31;
    const int q0 = qb * 256;
    const int wq0 = q0 + w * 32;
    const int qg = wq0 + q31;
    const int xr = q31 & 7;

    __shared__ bf16 Kl[2][64 * 64];
    __shared__ bf16 Vl[2][64 * 64];

    const bf16* Kbase = Kh + (size_t)bh * TT * HD;
    const bf16* Vbase = Vt + (size_t)bh * HD * TT;

    // Q B-operand fragments: lane holds Q[qg][ds*16 + hi*8 + 0..7]
    bf16x8 qF[4];
    {
        const bf16* qp = Qh + (size_t)bh * TT * HD + (size_t)qg * HD + hi * 8;
        #pragma unroll
        for (int ds = 0; ds < 4; ++ds) qF[ds] = *(const bf16x8*)(qp + ds * 16);
    }

    f32x16 accY[2];
    #pragma unroll
    for (int i = 0; i < 16; ++i) { accY[0][i] = 0.f; accY[1][i] = 0.f; }
    float mR = -INFINITY, lR = 0.f;

    const int srow = lane >> 3;                 // 0..7
    const int schunk = (lane & 7) ^ srow;       // pre-swizzled source chunk
    const int ktN = 4 * qb + 4;

    // prologue: stage kt=0 into buf 0 (wave w stages rows w*8..w*8+7)
    {
        int trow = w * 8 + srow;
        gload16(Kbase + (size_t)trow * HD + schunk * 8, &Kl[0][w * 512]);
        gload16(Vbase + (size_t)trow * TT + schunk * 8, &Vl[0][w * 512]);
    }
    __syncthreads();

    int cur = 0;
    for (int kt = 0; kt < ktN; ++kt) {
        if (kt + 1 < ktN) {
            int trow = (kt + 1) * 64 + w * 8 + srow;
            int drow = w * 8 + srow;
            gload16(Kbase + (size_t)trow * HD + schunk * 8, &Kl[cur ^ 1][w * 512]);
            gload16(Vbase + (size_t)drow * TT + (kt + 1) * 64 + schunk * 8,
                    &Vl[cur ^ 1][w * 512]);
        }
        if (kt * 64 <= wq0 + 31) {   // wave participates in this tile
            const bf16* KL = &Kl[cur][0];
            const bf16* VL = &Vl[cur][0];
            // ---- S^T = K @ Q^T : rows k (32 per frag), cols q ----
            f32x16 sa[2];
            #pragma unroll
            for (int i = 0; i < 16; ++i) { sa[0][i] = 0.f; sa[1][i] = 0.f; }
            #pragma unroll
            for (int ds = 0; ds < 4; ++ds) {
                int cc = ds * 2 + hi;
                bf16x8 k0 = *(const bf16x8*)&KL[q31 * 64 + ((cc ^ xr) * 8)];
                bf16x8 k1 = *(const bf16x8*)&KL[(32 + q31) * 64 + ((cc ^ xr) * 8)];
                sa[0] = __builtin_amdgcn_mfma_f32_32x32x16_bf16(k0, qF[ds], sa[0], 0, 0, 0);
                sa[1] = __builtin_amdgcn_mfma_f32_32x32x16_bf16(k1, qF[ds], sa[1], 0, 0, 0);
            }
            // ---- causal mask (only near-diagonal tiles) ----
            if (kt * 64 + 63 > wq0) {
                #pragma unroll
                for (int kb = 0; kb < 2; ++kb)
                    #pragma unroll
                    for (int r = 0; r < 16; ++r) {
                        int k = kt * 64 + kb * 32 + (r & 3) + 8 * (r >> 2) + 4 * hi;
                        if (k > qg) sa[kb][r] = -1e30f;
                    }
            }
            // ---- in-register online softmax (q = lane column) ----
            float mx = -1e30f;
            #pragma unroll
            for (int r = 0; r < 16; ++r) {
                mx = fmaxf(mx, sa[0][r]);
                mx = fmaxf(mx, sa[1][r]);
            }
            mx = fmaxf(mx, __shfl_xor(mx, 32, 64));
            float mnew = fmaxf(mR, mx);
            float alpha = __expf(mR - mnew);
            float sum = 0.f;
            #pragma unroll
            for (int kb = 0; kb < 2; ++kb)
                #pragma unroll
                for (int r = 0; r < 16; ++r) {
                    float p = __expf(sa[kb][r] - mnew);
                    sa[kb][r] = p;
                    sum += p;
                }
            sum += __shfl_xor(sum, 32, 64);
            lR = lR * alpha + sum;
            mR = mnew;
            #pragma unroll
            for (int i = 0; i < 16; ++i) { accY[0][i] *= alpha; accY[1][i] *= alpha; }
            // ---- pack P to bf16 words, exchange halves, build B-frags ----
            unsigned int wds[2][8];
            #pragma unroll
            for (int kb = 0; kb < 2; ++kb)
                #pragma unroll
                for (int j = 0; j < 8; ++j) {
                    bf16x8 tmp;   // only low 2 used
                    tmp[0] = (bf16)sa[kb][2 * j];
                    tmp[1] = (bf16)sa[kb][2 * j + 1];
                    wds[kb][j] = *(unsigned int*)&tmp;
                }
            bf16x8 pF[4];
            #pragma unroll
            for (int ks = 0; ks < 4; ++ks) {
                const int kb = ks >> 1, s = ks & 1;
                unsigned int w0 = wds[kb][4 * s + 0], w1 = wds[kb][4 * s + 1];
                unsigned int w2 = wds[kb][4 * s + 2], w3 = wds[kb][4 * s + 3];
                unsigned int t0 = hi ? w0 : w2, t1 = hi ? w1 : w3;
                unsigned int r0 = (unsigned int)__shfl_xor((int)t0, 32, 64);
                unsigned int r1 = (unsigned int)__shfl_xor((int)t1, 32, 64);
                uint32x4 fw;
                fw[0] = hi ? r0 : w0; fw[1] = hi ? r1 : w1;
                fw[2] = hi ? w2 : r0; fw[3] = hi ? w3 : r1;
                pF[ks] = *(bf16x8*)&fw;
            }
            // ---- Y^T += V^T @ P^T ----
            #pragma unroll
            for (int cd = 0; cd < 2; ++cd) {
                const int rowD = cd * 32 + q31;
                #pragma unroll
                for (int ks = 0; ks < 4; ++ks) {
                    int cc = ks * 2 + hi;
                    bf16x8 vA = *(const bf16x8*)&VL[rowD * 64 + ((cc ^ xr) * 8)];
                    accY[cd] = __builtin_amdgcn_mfma_f32_32x32x16_bf16(
                        vA, pF[ks], accY[cd], 0, 0, 0);
                }
            }
        }
        __syncthreads();
        cur ^= 1;
    }

    // epilogue: Y[qg][h*64 + d] = accY/l ; d = cd*32 + 8g + 4hi + 0..3
    float inv = 1.0f / lR;
    bf16* yp = Y + ((size_t)(b * TT + qg)) * CC + h * HD;
    #pragma unroll
    for (int cd = 0; cd < 2; ++cd)
        #pragma unroll
        for (int g = 0; g < 4; ++g) {
            int d0 = cd * 32 + 8 * g + 4 * hi;
            bf16x4 o;
            o[0] = (bf16)(accY[cd][4 * g + 0] * inv);
            o[1] = (bf16)(accY[cd][4 * g + 1] * inv);
            o[2] = (bf16)(accY[cd][4 * g + 2] * inv);
            o[3] = (bf16)(accY[cd][4 * g + 3] * inv);
            *(bf16x4*)(yp + d0) = o;
        }
}

extern "C" void kernel_launch(void* const* d_in, const int* in_sizes, int n_in,
                              void* d_out, int out_size, void* d_ws, size_t ws_size,
                              hipStream_t stream) {
    const float* x         = (const float*)d_in[0];
    const float* w_attn    = (const float*)d_in[1];
    const float* w_proj    = (const float*)d_in[2];
    const float* val_embed = (const float*)d_in[3];
    float* out = (float*)d_out;

    bf16* xb  = (bf16*)d_ws;                        // 8192*1024
    bf16* waT = xb + (size_t)8192 * 1024;           // 3072*1024
    bf16* wpT = waT + (size_t)3072 * 1024;          // 1024*1024
    bf16* Qh  = wpT + (size_t)1024 * 1024;          // 64*2048*64
    bf16* Kh  = Qh + (size_t)64 * 2048 * 64;
    bf16* Vh  = Kh + (size_t)64 * 2048 * 64;
    bf16* Vt  = Vh + (size_t)64 * 2048 * 64;
    bf16* Yb  = Vt + (size_t)64 * 2048 * 64;
    float* tab = (float*)(Yb + (size_t)64 * 2048 * 64);  // 2*2048*32 f32

    rope_table_k<<<dim3((TT * 32 + 255) / 256), dim3(256), 0, stream>>>(tab);
    cvt_f2b_k<<<dim3(8192 * 1024 / 8 / 256), dim3(256), 0, stream>>>(x, xb, 8192 * 1024 / 8);
    transW_k<<<dim3(3072 / 64, 1024 / 64), dim3(256), 0, stream>>>(w_attn, waT, 1024, 3072);
    transW_k<<<dim3(1024 / 64, 1024 / 64), dim3(256), 0, stream>>>(w_proj, wpT, 1024, 1024);
    gemm_bt_k<<<dim3(3072 / 128, 8192 / 128), dim3(256), 0, stream>>>(
        xb, waT, nullptr, Qh, Kh, Vh, 8192, 3072, 1024, 1);
    rope_rms_k<<<dim3(BB * HH * TT / 4), dim3(256), 0, stream>>>(Qh, Kh, Vh, val_embed, tab);
    transV_k<<<dim3(TT / 64, BB * HH), dim3(256), 0, stream>>>(Vh, Vt);
    attn_k<<<dim3(8, BB * HH), dim3(512), 0, stream>>>(Qh, Kh, Vt, Yb);
    gemm_bt_k<<<dim3(1024 / 128, 8192 / 128), dim3(256), 0, stream>>>(
        Yb, wpT, out, nullptr, nullptr, nullptr, 8192, 1024, 1024, 0);
}